// Round 3
// baseline (32794.925 us; speedup 1.0000x reference)
//
#include <hip/hip_runtime.h>
#include <stdint.h>

// B=64, L=128, H=512, LAB=128. 8192 strictly-sequential LSTM cell steps
// sharing one (h,c) of size 512:
//   gates[s] = pre[s] + W_p @ h[s-64] + W_hh @ h[s-1]
//   pre[s]   = W_ih[:, :2048] @ [x;hi] + b_ih + b_hh     (parallel GEMM)
//
// ws layout (needs 48MB, verified available in R2):
//   [0,32MB)  pre32: bf16-pair-packed u32 [8192][1024]  ([s][g*256 + j>>1])
//   [32,48MB) units: u32 [8192][512], unit = (tag16 << 16) | bf16(h[j])
//             tag = step+1 (1..8192); 0xAA poison tag = 0xAAAA never aliases.
//
// lstm_seq: 512 waves (128 WG x 256 thr), wave j owns h-lane j. Weights for
// rows {g*512+j} live in VGPRs (64 fp32/lane). NO barriers / LDS in the scan
// loop; cross-wave sync is purely tagged-unit publish/poll at agent scope.

#define HDIM   512
#define NSTEP  8192
#define XDIM   2048
#define IN5H   2560
#define LSEQ   128
#define LAB    128
#define SPIN_LIMIT 65536

typedef float f32x4 __attribute__((ext_vector_type(4)));
typedef short bf16x8 __attribute__((ext_vector_type(8)));

__device__ __forceinline__ unsigned f2bf(float v){
  unsigned u = __float_as_uint(v);
  u += 0x7fffu + ((u >> 16) & 1u);      // RNE; values bounded (no NaN/Inf)
  return u >> 16;
}
__device__ __forceinline__ float bf2f_lo(unsigned w){ return __uint_as_float((w & 0xffffu) << 16); }
__device__ __forceinline__ float bf2f_hi(unsigned w){ return __uint_as_float(w & 0xffff0000u); }

// ---------------------------------------------------------------- phase 1
// pre[s][r] = sum_k xcat[s][k]*W_ih[r][k] + b_ih[r] + b_hh[r], bf16-packed.
__global__ __launch_bounds__(256) void gemm_pre(
    const float* __restrict__ x, const float* __restrict__ hi,
    const float* __restrict__ Wih, const float* __restrict__ bih,
    const float* __restrict__ bhh, unsigned* __restrict__ pre32)
{
  __shared__ unsigned short As[128][40];   // +8 pad, 16B-aligned b128 reads
  __shared__ unsigned short Bs[128][40];
  const int tid = threadIdx.x;
  const int bm = blockIdx.x, bn = blockIdx.y;
  const int lane = tid & 63, wv = tid >> 6;
  const int wm = wv & 1, wn = wv >> 1;

  const int srow = tid >> 1;              // staging row 0..127
  const int ch   = (tid & 1) * 16;        // col half of the 32-wide K chunk

  const int gr = bm*128 + srow;           // global s row
  const int bb = gr & 63, tt = gr >> 6;   // s = t*64 + b
  const float* ax = x  + (size_t)(bb*LSEQ + tt) * 1024;
  const float* ah = hi + (size_t)(bb*LSEQ + tt) * 1024;
  const int R = bn*128 + srow;            // global gate row
  const float* bw = Wih + (size_t)R * IN5H;

  f32x4 acc[4][4];
  #pragma unroll
  for (int m=0;m<4;++m)
    #pragma unroll
    for (int n=0;n<4;++n) acc[m][n] = (f32x4){0.f,0.f,0.f,0.f};

  for (int kc = 0; kc < XDIM; kc += 32){
    const int c0 = kc + ch;
    const float* ap = (c0 < 1024) ? (ax + c0) : (ah + (c0 - 1024));
    #pragma unroll
    for (int q=0;q<4;++q){
      float4 va = *(const float4*)(ap + 4*q);
      float4 vb = *(const float4*)(bw + c0 + 4*q);
      ushort4 ua; ua.x=f2bf(va.x); ua.y=f2bf(va.y); ua.z=f2bf(va.z); ua.w=f2bf(va.w);
      ushort4 ub; ub.x=f2bf(vb.x); ub.y=f2bf(vb.y); ub.z=f2bf(vb.z); ub.w=f2bf(vb.w);
      *(ushort4*)&As[srow][ch + 4*q] = ua;
      *(ushort4*)&Bs[srow][ch + 4*q] = ub;
    }
    __syncthreads();
    bf16x8 afr[4], bfr[4];
    const int mr = wm*64 + (lane & 15);
    const int nr = wn*64 + (lane & 15);
    const int ko = (lane >> 4) * 8;
    #pragma unroll
    for (int m=0;m<4;++m) afr[m] = *(const bf16x8*)&As[mr + 16*m][ko];
    #pragma unroll
    for (int n=0;n<4;++n) bfr[n] = *(const bf16x8*)&Bs[nr + 16*n][ko];
    #pragma unroll
    for (int m=0;m<4;++m)
      #pragma unroll
      for (int n=0;n<4;++n)
        acc[m][n] = __builtin_amdgcn_mfma_f32_16x16x32_bf16(afr[m], bfr[n], acc[m][n], 0, 0, 0);
    __syncthreads();
  }
  // C/D layout: col = lane&15 (N side), row = (lane>>4)*4+q (M side)
  #pragma unroll
  for (int n=0;n<4;++n){
    const int scol = bn*128 + wn*64 + 16*n + (lane & 15);
    const float bias = bih[scol] + bhh[scol];
    #pragma unroll
    for (int m=0;m<4;++m){
      const int sr0 = bm*128 + wm*64 + 16*m + (lane >> 4)*4;
      #pragma unroll
      for (int q=0;q<4;++q){
        const float v = acc[m][n][q] + bias;
        const float vn = __shfl_xor(v, 1, 64);     // neighbor col (scol^1)
        if (!(lane & 1)){
          const unsigned word = f2bf(v) | (f2bf(vn) << 16);
          pre32[(size_t)(sr0 + q) * 1024 + (scol >> 1)] = word;
        }
      }
    }
  }
}

// ---------------------------------------------------------------- phase 2
// 512 independent waves; wave j0 owns h-lane j0 (gate rows {g*512+j0}).
// Lane l holds weight cols {l + 64c}. No LDS, no barriers in the loop.
__global__ __launch_bounds__(256, 1) void lstm_seq(
    const float* __restrict__ Wih, const float* __restrict__ Whh,
    const unsigned* __restrict__ pre32, unsigned* __restrict__ units)
{
  const int tid = threadIdx.x;
  const int l = tid & 63;
  const int j0 = blockIdx.x * 4 + (tid >> 6);      // 0..511

  // ---- weights into VGPRs (once): 4 gates x 8 cols, h-part + u-part ----
  float wh[4][8], wu[4][8];
  #pragma unroll
  for (int g=0; g<4; ++g){
    const float* ph = Whh + (size_t)(g*HDIM + j0)*HDIM;
    const float* pu = Wih + (size_t)(g*HDIM + j0)*IN5H + XDIM;
    #pragma unroll
    for (int c=0; c<8; ++c){ wh[g][c] = ph[l + 64*c]; wu[g][c] = pu[l + 64*c]; }
  }

  const int phalf = j0 >> 1, psel = j0 & 1;
  float pr[4];
  #pragma unroll
  for (int g=0; g<4; ++g){
    const unsigned w0 = pre32[(size_t)0*1024 + g*256 + phalf];
    pr[g] = psel ? bf2f_hi(w0) : bf2f_lo(w0);
  }

  float cst = 0.f;
  int dead = 0;

  for (int s = 0; s < NSTEP; ++s){
    float hv[8], uv[8];
    // ---- poll h[s-1] (tag s), decode to registers ----
    if (s == 0){
      #pragma unroll
      for (int c=0;c<8;++c) hv[c] = 0.f;
    } else {
      const unsigned* bp = units + (size_t)(s-1)*HDIM + l;
      unsigned v[8];
      if (dead){
        #pragma unroll
        for (int c=0;c<8;++c) v[c] = __hip_atomic_load(bp + 64*c, __ATOMIC_RELAXED, __HIP_MEMORY_SCOPE_AGENT);
      } else {
        int trips = 0, ok;
        do {
          #pragma unroll
          for (int c=0;c<8;++c) v[c] = __hip_atomic_load(bp + 64*c, __ATOMIC_RELAXED, __HIP_MEMORY_SCOPE_AGENT);
          int lok = 1;
          #pragma unroll
          for (int c=0;c<8;++c) lok &= ((v[c] >> 16) == (unsigned)s);
          ok = __all(lok);
        } while (!ok && ++trips < SPIN_LIMIT);
        if (!ok) dead = 1;
      }
      #pragma unroll
      for (int c=0;c<8;++c) hv[c] = bf2f_lo(v[c]);
    }
    // ---- u = h[s-64] (tag s-63): 63-step slack, no spin in practice ----
    if (s >= 64){
      const unsigned* bp = units + (size_t)(s-64)*HDIM + l;
      unsigned v[8];
      if (dead){
        #pragma unroll
        for (int c=0;c<8;++c) v[c] = __hip_atomic_load(bp + 64*c, __ATOMIC_RELAXED, __HIP_MEMORY_SCOPE_AGENT);
      } else {
        int trips = 0, ok;
        do {
          #pragma unroll
          for (int c=0;c<8;++c) v[c] = __hip_atomic_load(bp + 64*c, __ATOMIC_RELAXED, __HIP_MEMORY_SCOPE_AGENT);
          int lok = 1;
          #pragma unroll
          for (int c=0;c<8;++c) lok &= ((v[c] >> 16) == (unsigned)(s-63));
          ok = __all(lok);
        } while (!ok && ++trips < SPIN_LIMIT);
        if (!ok) dead = 1;
      }
      #pragma unroll
      for (int c=0;c<8;++c) uv[c] = bf2f_lo(v[c]);
    } else {
      #pragma unroll
      for (int c=0;c<8;++c) uv[c] = 0.f;
    }

    // ---- prefetch pre[s+1] (independent, hides latency) ----
    float prn[4];
    if (s + 1 < NSTEP){
      #pragma unroll
      for (int g=0; g<4; ++g){
        const unsigned w0 = pre32[(size_t)(s+1)*1024 + g*256 + phalf];
        prn[g] = psel ? bf2f_hi(w0) : bf2f_lo(w0);
      }
    } else {
      #pragma unroll
      for (int g=0; g<4; ++g) prn[g] = 0.f;
    }

    // ---- matvec: 4 gate rows x (8 h-cols + 8 u-cols) ----
    float a0=0.f, a1=0.f, a2=0.f, a3=0.f;
    #pragma unroll
    for (int c=0;c<8;++c){
      a0 += wh[0][c]*hv[c]; a1 += wh[1][c]*hv[c];
      a2 += wh[2][c]*hv[c]; a3 += wh[3][c]*hv[c];
    }
    #pragma unroll
    for (int c=0;c<8;++c){
      a0 += wu[0][c]*uv[c]; a1 += wu[1][c]*uv[c];
      a2 += wu[2][c]*uv[c]; a3 += wu[3][c]*uv[c];
    }
    #pragma unroll
    for (int off=32; off>=1; off>>=1){
      a0 += __shfl_xor(a0, off, 64);
      a1 += __shfl_xor(a1, off, 64);
      a2 += __shfl_xor(a2, off, 64);
      a3 += __shfl_xor(a3, off, 64);
    }

    // ---- pointwise (redundant across lanes; bit-identical) ----
    float gi = a0 + pr[0];
    float gf = a1 + pr[1];
    float gg = a2 + pr[2];
    float go = a3 + pr[3];
    gi = 1.f/(1.f + __expf(-gi));
    gf = 1.f/(1.f + __expf(-gf));
    go = 1.f/(1.f + __expf(-go));
    float e2 = __expf(2.f * fminf(fmaxf(gg, -15.f), 15.f));
    gg = (e2 - 1.f) / (e2 + 1.f);
    cst = gf*cst + gi*gg;
    float e2c = __expf(2.f * fminf(fmaxf(cst, -15.f), 15.f));
    const float hval = go * ((e2c - 1.f) / (e2c + 1.f));

    // ---- publish: lane 0 stores self-tagged unit ----
    if (l == 0){
      const unsigned unit = ((unsigned)(s + 1) << 16) | f2bf(hval);
      __hip_atomic_store(units + (size_t)s*HDIM + j0, unit,
                         __ATOMIC_RELAXED, __HIP_MEMORY_SCOPE_AGENT);
    }
    #pragma unroll
    for (int g=0; g<4; ++g) pr[g] = prn[g];
  }
}

// ---------------------------------------------------------------- phase 3
// y[b][t][lab] = sum_j h[s][j] * W_fc[lab][j] + b_fc[lab],  s = t*64 + b
__global__ __launch_bounds__(256) void fc_kernel(
    const unsigned* __restrict__ units,
    const float* __restrict__ Wfc, const float* __restrict__ bfc,
    float* __restrict__ out)
{
  __shared__ float hbuf[8][512];
  const int tid = threadIdx.x;
  const int s0 = blockIdx.x * 8;
  #pragma unroll
  for (int r=0;r<16;++r){
    const int q = tid + 256*r;                 // 0..4095
    const int si = q >> 9, j = q & 511;
    hbuf[si][j] = bf2f_lo(units[(size_t)(s0 + si)*HDIM + j]);
  }
  __syncthreads();
  const int lab = tid & 127, sg = tid >> 7;
  const float* wrow = Wfc + (size_t)lab * HDIM;
  const float bias = bfc[lab];
  for (int si = sg; si < 8; si += 2){
    float sum = 0.f;
    #pragma unroll 4
    for (int j=0;j<HDIM;j+=4){
      const float4 wv = *(const float4*)(wrow + j);
      sum += wv.x*hbuf[si][j] + wv.y*hbuf[si][j+1]
           + wv.z*hbuf[si][j+2] + wv.w*hbuf[si][j+3];
    }
    const int s = s0 + si;
    const int bb = s & 63, tt = s >> 6;
    out[((size_t)(bb*LSEQ + tt))*LAB + lab] = sum + bias;
  }
}

__global__ void sentinel_kernel(float* out, int n){
  const int i = blockIdx.x*256 + threadIdx.x;
  if (i < n) out[i] = 12345.0f;     // diagnostic: ws_size too small
}

extern "C" void kernel_launch(void* const* d_in, const int* in_sizes, int n_in,
                              void* d_out, int out_size, void* d_ws, size_t ws_size,
                              hipStream_t stream)
{
  const float* x   = (const float*)d_in[0];
  const float* hi  = (const float*)d_in[1];
  const float* Wih = (const float*)d_in[2];
  const float* Whh = (const float*)d_in[3];
  const float* bih = (const float*)d_in[4];
  const float* bhh = (const float*)d_in[5];
  const float* Wfc = (const float*)d_in[6];
  const float* bfc = (const float*)d_in[7];
  float* out = (float*)d_out;

  const size_t MB = 1024*1024;
  if (ws_size >= 48*MB){
    unsigned* pre32 = (unsigned*)d_ws;                          // 32MB
    unsigned* units = (unsigned*)((char*)d_ws + 32*MB);         // 16MB
    gemm_pre<<<dim3(64, 16), 256, 0, stream>>>(x, hi, Wih, bih, bhh, pre32);
    lstm_seq<<<128, 256, 0, stream>>>(Wih, Whh, pre32, units);
    fc_kernel<<<1024, 256, 0, stream>>>(units, Wfc, bfc, out);
  } else {
    sentinel_kernel<<<(out_size + 255)/256, 256, 0, stream>>>(out, out_size);
  }
}

// Round 4
// 16129.443 us; speedup vs baseline: 2.0332x; 2.0332x over previous
//
#include <hip/hip_runtime.h>
#include <stdint.h>

// B=64, L=128, H=512, LAB=128. 8192 strictly-sequential LSTM cell steps
// sharing one (h,c) of size 512:
//   gates[s] = pre[s] + W_p @ h[s-64] + W_hh @ h[s-1]
//   pre[s]   = W_ih[:, :2048] @ [x;hi] + b_ih + b_hh     (parallel GEMM)
//
// ws layout (needs 48MB):
//   [0,32MB)  pre32: bf16-pair-packed u32 [8192][1024]  ([s][g*256 + j>>1])
//   [32,48MB) units: u32 [8192][512], unit = (tag16 << 16) | bf16(h[j])
//             tag = step+1 (1..8192); 0xAA poison tag = 0xAAAA never aliases.
//
// lstm_seq: 512 waves (128 WG x 256 thr), wave j owns h-lane j. Weights
// PINNED in VGPRs via asm barrier (R3 bug: compiler sank the invariant loads
// into the loop -> VGPR_Count 56 + 64 global loads/thread/step). All global
// reads for step s+1 (u = h[s-63], pre[s+1]) are issued BEFORE the h[s-1]
// spin so the whole step pays ONE round-trip latency (R3 paid 2-3 serial).

#define HDIM   512
#define NSTEP  8192
#define XDIM   2048
#define IN5H   2560
#define LSEQ   128
#define LAB    128
#define SPIN_LIMIT 65536

typedef float f32x4 __attribute__((ext_vector_type(4)));
typedef short bf16x8 __attribute__((ext_vector_type(8)));

__device__ __forceinline__ unsigned f2bf(float v){
  unsigned u = __float_as_uint(v);
  u += 0x7fffu + ((u >> 16) & 1u);      // RNE; values bounded (no NaN/Inf)
  return u >> 16;
}
__device__ __forceinline__ float bf2f_lo(unsigned w){ return __uint_as_float(w << 16); }
__device__ __forceinline__ float bf2f_hi(unsigned w){ return __uint_as_float(w & 0xffff0000u); }

// ---------------------------------------------------------------- phase 1
// pre[s][r] = sum_k xcat[s][k]*W_ih[r][k] + b_ih[r] + b_hh[r], bf16-packed.
__global__ __launch_bounds__(256) void gemm_pre(
    const float* __restrict__ x, const float* __restrict__ hi,
    const float* __restrict__ Wih, const float* __restrict__ bih,
    const float* __restrict__ bhh, unsigned* __restrict__ pre32)
{
  __shared__ unsigned short As[128][40];   // +8 pad, 16B-aligned b128 reads
  __shared__ unsigned short Bs[128][40];
  const int tid = threadIdx.x;
  const int bm = blockIdx.x, bn = blockIdx.y;
  const int lane = tid & 63, wv = tid >> 6;
  const int wm = wv & 1, wn = wv >> 1;

  const int srow = tid >> 1;              // staging row 0..127
  const int ch   = (tid & 1) * 16;        // col half of the 32-wide K chunk

  const int gr = bm*128 + srow;           // global s row
  const int bb = gr & 63, tt = gr >> 6;   // s = t*64 + b
  const float* ax = x  + (size_t)(bb*LSEQ + tt) * 1024;
  const float* ah = hi + (size_t)(bb*LSEQ + tt) * 1024;
  const int R = bn*128 + srow;            // global gate row
  const float* bw = Wih + (size_t)R * IN5H;

  f32x4 acc[4][4];
  #pragma unroll
  for (int m=0;m<4;++m)
    #pragma unroll
    for (int n=0;n<4;++n) acc[m][n] = (f32x4){0.f,0.f,0.f,0.f};

  for (int kc = 0; kc < XDIM; kc += 32){
    const int c0 = kc + ch;
    const float* ap = (c0 < 1024) ? (ax + c0) : (ah + (c0 - 1024));
    #pragma unroll
    for (int q=0;q<4;++q){
      float4 va = *(const float4*)(ap + 4*q);
      float4 vb = *(const float4*)(bw + c0 + 4*q);
      ushort4 ua; ua.x=f2bf(va.x); ua.y=f2bf(va.y); ua.z=f2bf(va.z); ua.w=f2bf(va.w);
      ushort4 ub; ub.x=f2bf(vb.x); ub.y=f2bf(vb.y); ub.z=f2bf(vb.z); ub.w=f2bf(vb.w);
      *(ushort4*)&As[srow][ch + 4*q] = ua;
      *(ushort4*)&Bs[srow][ch + 4*q] = ub;
    }
    __syncthreads();
    bf16x8 afr[4], bfr[4];
    const int mr = wm*64 + (lane & 15);
    const int nr = wn*64 + (lane & 15);
    const int ko = (lane >> 4) * 8;
    #pragma unroll
    for (int m=0;m<4;++m) afr[m] = *(const bf16x8*)&As[mr + 16*m][ko];
    #pragma unroll
    for (int n=0;n<4;++n) bfr[n] = *(const bf16x8*)&Bs[nr + 16*n][ko];
    #pragma unroll
    for (int m=0;m<4;++m)
      #pragma unroll
      for (int n=0;n<4;++n)
        acc[m][n] = __builtin_amdgcn_mfma_f32_16x16x32_bf16(afr[m], bfr[n], acc[m][n], 0, 0, 0);
    __syncthreads();
  }
  // C/D layout: col = lane&15 (N side), row = (lane>>4)*4+q (M side)
  #pragma unroll
  for (int n=0;n<4;++n){
    const int scol = bn*128 + wn*64 + 16*n + (lane & 15);
    const float bias = bih[scol] + bhh[scol];
    #pragma unroll
    for (int m=0;m<4;++m){
      const int sr0 = bm*128 + wm*64 + 16*m + (lane >> 4)*4;
      #pragma unroll
      for (int q=0;q<4;++q){
        const float v = acc[m][n][q] + bias;
        const float vn = __shfl_xor(v, 1, 64);     // neighbor col (scol^1)
        if (!(lane & 1)){
          const unsigned word = f2bf(v) | (f2bf(vn) << 16);
          pre32[(size_t)(sr0 + q) * 1024 + (scol >> 1)] = word;
        }
      }
    }
  }
}

// ---------------------------------------------------------------- phase 2
// 512 independent waves; wave j0 owns h-lane j0 (gate rows {g*512+j0}).
// Lane l holds weight cols {l + 64c}. No LDS, no barriers in the loop.
__global__ __launch_bounds__(256, 1) void lstm_seq(
    const float* __restrict__ Wih, const float* __restrict__ Whh,
    const unsigned* __restrict__ pre32, unsigned* __restrict__ units)
{
  const int tid = threadIdx.x;
  const int l = tid & 63;
  const int j0 = blockIdx.x * 4 + (tid >> 6);      // 0..511

  // ---- weights into VGPRs (once): 4 gates x 8 cols, h-part + u-part ----
  float wh[4][8], wu[4][8];
  #pragma unroll
  for (int g=0; g<4; ++g){
    const float* ph = Whh + (size_t)(g*HDIM + j0)*HDIM;
    const float* pu = Wih + (size_t)(g*HDIM + j0)*IN5H + XDIM;
    #pragma unroll
    for (int c=0; c<8; ++c){ wh[g][c] = ph[l + 64*c]; wu[g][c] = pu[l + 64*c]; }
  }
  // Pin: opaque asm def blocks rematerialization/sinking of the loads.
  #pragma unroll
  for (int g=0; g<4; ++g)
    #pragma unroll
    for (int c=0; c<8; ++c){
      asm volatile("" : "+v"(wh[g][c]));
      asm volatile("" : "+v"(wu[g][c]));
    }

  const int phalf = j0 >> 1, psel = j0 & 1;
  float pr[4];
  #pragma unroll
  for (int g=0; g<4; ++g){
    const unsigned w0 = pre32[(size_t)0*1024 + g*256 + phalf];
    pr[g] = psel ? bf2f_hi(w0) : bf2f_lo(w0);
  }

  float uvc[8];                       // u for current step (decoded)
  #pragma unroll
  for (int c=0;c<8;++c) uvc[c] = 0.f;

  float cst = 0.f;
  int dead = 0;

  for (int s = 0; s < NSTEP; ++s){
    // ---- issue ALL next-step loads first (share the poll's RT window) ----
    unsigned pw[4];
    const bool pf  = (s + 1 < NSTEP);
    const bool upf = (s + 1 >= 64) && pf;
    if (pf){
      #pragma unroll
      for (int g=0; g<4; ++g)
        pw[g] = pre32[(size_t)(s+1)*1024 + g*256 + phalf];   // plain, cached
    }
    unsigned un[8];
    if (upf){
      const unsigned* bp = units + (size_t)(s-63)*HDIM + l;  // u(s+1)=h[s-63]
      #pragma unroll
      for (int c=0;c<8;++c)
        un[c] = __hip_atomic_load(bp + 64*c, __ATOMIC_RELAXED, __HIP_MEMORY_SCOPE_AGENT);
    }

    // ---- poll h[s-1] (tag s) ----
    float hv[8];
    if (s == 0){
      #pragma unroll
      for (int c=0;c<8;++c) hv[c] = 0.f;
    } else {
      const unsigned* bp = units + (size_t)(s-1)*HDIM + l;
      unsigned v[8];
      if (dead){
        #pragma unroll
        for (int c=0;c<8;++c) v[c] = __hip_atomic_load(bp + 64*c, __ATOMIC_RELAXED, __HIP_MEMORY_SCOPE_AGENT);
      } else {
        int trips = 0, ok;
        do {
          #pragma unroll
          for (int c=0;c<8;++c) v[c] = __hip_atomic_load(bp + 64*c, __ATOMIC_RELAXED, __HIP_MEMORY_SCOPE_AGENT);
          int lok = 1;
          #pragma unroll
          for (int c=0;c<8;++c) lok &= ((v[c] >> 16) == (unsigned)s);
          ok = __all(lok);
        } while (!ok && ++trips < SPIN_LIMIT);
        if (!ok) dead = 1;
      }
      #pragma unroll
      for (int c=0;c<8;++c) hv[c] = bf2f_lo(v[c] & 0xffffu);
    }

    // ---- matvec: 4 gate rows x (8 h-cols + 8 u-cols) ----
    float a0=0.f, a1=0.f, a2=0.f, a3=0.f;
    #pragma unroll
    for (int c=0;c<8;++c){
      a0 += wh[0][c]*hv[c]; a1 += wh[1][c]*hv[c];
      a2 += wh[2][c]*hv[c]; a3 += wh[3][c]*hv[c];
    }
    #pragma unroll
    for (int c=0;c<8;++c){
      a0 += wu[0][c]*uvc[c]; a1 += wu[1][c]*uvc[c];
      a2 += wu[2][c]*uvc[c]; a3 += wu[3][c]*uvc[c];
    }
    #pragma unroll
    for (int off=32; off>=1; off>>=1){
      a0 += __shfl_xor(a0, off, 64);
      a1 += __shfl_xor(a1, off, 64);
      a2 += __shfl_xor(a2, off, 64);
      a3 += __shfl_xor(a3, off, 64);
    }

    // ---- pointwise (redundant across lanes; bit-identical) ----
    float gi = a0 + pr[0];
    float gf = a1 + pr[1];
    float gg = a2 + pr[2];
    float go = a3 + pr[3];
    gi = 1.f/(1.f + __expf(-gi));
    gf = 1.f/(1.f + __expf(-gf));
    go = 1.f/(1.f + __expf(-go));
    float e2 = __expf(2.f * fminf(fmaxf(gg, -15.f), 15.f));
    gg = (e2 - 1.f) / (e2 + 1.f);
    cst = gf*cst + gi*gg;
    float e2c = __expf(2.f * fminf(fmaxf(cst, -15.f), 15.f));
    const float hval = go * ((e2c - 1.f) / (e2c + 1.f));

    // ---- publish: lane 0 stores self-tagged unit ----
    if (l == 0){
      const unsigned unit = ((unsigned)(s + 1) << 16) | f2bf(hval);
      __hip_atomic_store(units + (size_t)s*HDIM + j0, unit,
                         __ATOMIC_RELAXED, __HIP_MEMORY_SCOPE_AGENT);
    }

    // ---- finalize prefetches (off critical path) ----
    if (upf){
      int lok = 1;
      #pragma unroll
      for (int c=0;c<8;++c) lok &= ((un[c] >> 16) == (unsigned)(s-62));
      if (!__all(lok) && !dead){
        // should never happen (62-step slack); bounded fallback spin
        const unsigned* bp = units + (size_t)(s-63)*HDIM + l;
        int trips = 0, ok;
        do {
          #pragma unroll
          for (int c=0;c<8;++c)
            un[c] = __hip_atomic_load(bp + 64*c, __ATOMIC_RELAXED, __HIP_MEMORY_SCOPE_AGENT);
          int lk = 1;
          #pragma unroll
          for (int c=0;c<8;++c) lk &= ((un[c] >> 16) == (unsigned)(s-62));
          ok = __all(lk);
        } while (!ok && ++trips < SPIN_LIMIT);
        if (!ok) dead = 1;
      }
      #pragma unroll
      for (int c=0;c<8;++c) uvc[c] = bf2f_lo(un[c] & 0xffffu);
    } else {
      #pragma unroll
      for (int c=0;c<8;++c) uvc[c] = 0.f;
    }
    if (pf){
      #pragma unroll
      for (int g=0; g<4; ++g) pr[g] = psel ? bf2f_hi(pw[g]) : bf2f_lo(pw[g] & 0xffffu);
    }
  }
}

// ---------------------------------------------------------------- phase 3
// y[b][t][lab] = sum_j h[s][j] * W_fc[lab][j] + b_fc[lab],  s = t*64 + b
__global__ __launch_bounds__(256) void fc_kernel(
    const unsigned* __restrict__ units,
    const float* __restrict__ Wfc, const float* __restrict__ bfc,
    float* __restrict__ out)
{
  __shared__ float hbuf[8][512];
  const int tid = threadIdx.x;
  const int s0 = blockIdx.x * 8;
  #pragma unroll
  for (int r=0;r<16;++r){
    const int q = tid + 256*r;                 // 0..4095
    const int si = q >> 9, j = q & 511;
    hbuf[si][j] = bf2f_lo(units[(size_t)(s0 + si)*HDIM + j] & 0xffffu);
  }
  __syncthreads();
  const int lab = tid & 127, sg = tid >> 7;
  const float* wrow = Wfc + (size_t)lab * HDIM;
  const float bias = bfc[lab];
  for (int si = sg; si < 8; si += 2){
    float sum = 0.f;
    #pragma unroll 4
    for (int j=0;j<HDIM;j+=4){
      const float4 wv = *(const float4*)(wrow + j);
      sum += wv.x*hbuf[si][j] + wv.y*hbuf[si][j+1]
           + wv.z*hbuf[si][j+2] + wv.w*hbuf[si][j+3];
    }
    const int s = s0 + si;
    const int bb = s & 63, tt = s >> 6;
    out[((size_t)(bb*LSEQ + tt))*LAB + lab] = sum + bias;
  }
}

__global__ void sentinel_kernel(float* out, int n){
  const int i = blockIdx.x*256 + threadIdx.x;
  if (i < n) out[i] = 12345.0f;     // diagnostic: ws_size too small
}

extern "C" void kernel_launch(void* const* d_in, const int* in_sizes, int n_in,
                              void* d_out, int out_size, void* d_ws, size_t ws_size,
                              hipStream_t stream)
{
  const float* x   = (const float*)d_in[0];
  const float* hi  = (const float*)d_in[1];
  const float* Wih = (const float*)d_in[2];
  const float* Whh = (const float*)d_in[3];
  const float* bih = (const float*)d_in[4];
  const float* bhh = (const float*)d_in[5];
  const float* Wfc = (const float*)d_in[6];
  const float* bfc = (const float*)d_in[7];
  float* out = (float*)d_out;

  const size_t MB = 1024*1024;
  if (ws_size >= 48*MB){
    unsigned* pre32 = (unsigned*)d_ws;                          // 32MB
    unsigned* units = (unsigned*)((char*)d_ws + 32*MB);         // 16MB
    gemm_pre<<<dim3(64, 16), 256, 0, stream>>>(x, hi, Wih, bih, bhh, pre32);
    lstm_seq<<<128, 256, 0, stream>>>(Wih, Whh, pre32, units);
    fc_kernel<<<1024, 256, 0, stream>>>(units, Wfc, bfc, out);
  } else {
    sentinel_kernel<<<(out_size + 255)/256, 256, 0, stream>>>(out, out_size);
  }
}

// Round 6
// 14518.419 us; speedup vs baseline: 2.2588x; 1.1110x over previous
//
#include <hip/hip_runtime.h>
#include <stdint.h>

// B=64, L=128, H=512, LAB=128. 8192 strictly-sequential LSTM cell steps
// sharing one (h,c) of size 512:
//   gates[s] = pre[s] + W_p @ h[s-64] + W_hh @ h[s-1]
//   pre[s]   = W_ih[:, :2048] @ [x;hi] + b_ih + b_hh     (parallel GEMM)
//
// ws layout (needs 48MB):
//   [0,32MB)  pre32: bf16-pair-packed u32 [8192][1024]  ([s][g*256 + j>>1])
//   [32,48MB) units: u32 [8192][512], unit = (tag16 << 16) | bf16(h[j])
//             tag = step+1 (1..8192); 0xAA poison tag = 0xAAAA never aliases.
//
// lstm_seq: 512 waves (128 WG x 256 thr), wave j0 owns h-lane j0.
//  - amdgpu_waves_per_eu(1,1): occupancy is structurally 1 wave/EU (128 WGs
//    on 256 CUs), so tell the allocator -> weights stay in VGPRs (R4 bug:
//    VGPR_Count=60, weights spilled to scratch, ~169MB HBM scratch traffic).
//  - poll = 4 x u64 relaxed agent atomic loads (each 4B half self-tagged).
//  - reduce via DPP (row_shr 1/2/4/8 + row_bcast 15/31) -> lane 63; publishes
//    from lane 63. Replaces 6-level ds_bpermute butterfly (LDS-pipe latency).
//  - all step-s+1 loads (u = h[s-63], pre[s+1]) issued BEFORE the h[s-1]
//    spin: one round-trip latency per step.
// (R5 fix: dpp ctrl must be a compile-time constant -> template param.)

#define HDIM   512
#define NSTEP  8192
#define XDIM   2048
#define IN5H   2560
#define LSEQ   128
#define LAB    128
#define SPIN_LIMIT 65536

typedef float f32x4 __attribute__((ext_vector_type(4)));
typedef short bf16x8 __attribute__((ext_vector_type(8)));

__device__ __forceinline__ unsigned f2bf(float v){
  unsigned u = __float_as_uint(v);
  u += 0x7fffu + ((u >> 16) & 1u);      // RNE; values bounded (no NaN/Inf)
  return u >> 16;
}
__device__ __forceinline__ float bfu(unsigned half16){   // bf16 bits -> f32
  return __uint_as_float(half16 << 16);
}
template<int CTRL>
__device__ __forceinline__ float dpp_add(float x){
  const int yi = __builtin_amdgcn_update_dpp(0, __float_as_int(x), CTRL, 0xF, 0xF, true);
  return x + __int_as_float(yi);
}
// sum of x across 64 lanes, valid in lane 63 (other lanes partial)
__device__ __forceinline__ float wave_reduce63(float x){
  x = dpp_add<0x111>(x);   // row_shr:1
  x = dpp_add<0x112>(x);   // row_shr:2
  x = dpp_add<0x114>(x);   // row_shr:4
  x = dpp_add<0x118>(x);   // row_shr:8  -> lane15+16k = row sum
  x = dpp_add<0x142>(x);   // row_bcast:15
  x = dpp_add<0x143>(x);   // row_bcast:31 -> lane 63 = total
  return x;
}

// ---------------------------------------------------------------- phase 1
// pre[s][r] = sum_k xcat[s][k]*W_ih[r][k] + b_ih[r] + b_hh[r], bf16-packed.
__global__ __launch_bounds__(256) void gemm_pre(
    const float* __restrict__ x, const float* __restrict__ hi,
    const float* __restrict__ Wih, const float* __restrict__ bih,
    const float* __restrict__ bhh, unsigned* __restrict__ pre32)
{
  __shared__ unsigned short As[128][40];   // +8 pad, 16B-aligned b128 reads
  __shared__ unsigned short Bs[128][40];
  const int tid = threadIdx.x;
  const int bm = blockIdx.x, bn = blockIdx.y;
  const int lane = tid & 63, wv = tid >> 6;
  const int wm = wv & 1, wn = wv >> 1;

  const int srow = tid >> 1;              // staging row 0..127
  const int ch   = (tid & 1) * 16;        // col half of the 32-wide K chunk

  const int gr = bm*128 + srow;           // global s row
  const int bb = gr & 63, tt = gr >> 6;   // s = t*64 + b
  const float* ax = x  + (size_t)(bb*LSEQ + tt) * 1024;
  const float* ah = hi + (size_t)(bb*LSEQ + tt) * 1024;
  const int R = bn*128 + srow;            // global gate row
  const float* bw = Wih + (size_t)R * IN5H;

  f32x4 acc[4][4];
  #pragma unroll
  for (int m=0;m<4;++m)
    #pragma unroll
    for (int n=0;n<4;++n) acc[m][n] = (f32x4){0.f,0.f,0.f,0.f};

  for (int kc = 0; kc < XDIM; kc += 32){
    const int c0 = kc + ch;
    const float* ap = (c0 < 1024) ? (ax + c0) : (ah + (c0 - 1024));
    #pragma unroll
    for (int q=0;q<4;++q){
      float4 va = *(const float4*)(ap + 4*q);
      float4 vb = *(const float4*)(bw + c0 + 4*q);
      ushort4 ua; ua.x=f2bf(va.x); ua.y=f2bf(va.y); ua.z=f2bf(va.z); ua.w=f2bf(va.w);
      ushort4 ub; ub.x=f2bf(vb.x); ub.y=f2bf(vb.y); ub.z=f2bf(vb.z); ub.w=f2bf(vb.w);
      *(ushort4*)&As[srow][ch + 4*q] = ua;
      *(ushort4*)&Bs[srow][ch + 4*q] = ub;
    }
    __syncthreads();
    bf16x8 afr[4], bfr[4];
    const int mr = wm*64 + (lane & 15);
    const int nr = wn*64 + (lane & 15);
    const int ko = (lane >> 4) * 8;
    #pragma unroll
    for (int m=0;m<4;++m) afr[m] = *(const bf16x8*)&As[mr + 16*m][ko];
    #pragma unroll
    for (int n=0;n<4;++n) bfr[n] = *(const bf16x8*)&Bs[nr + 16*n][ko];
    #pragma unroll
    for (int m=0;m<4;++m)
      #pragma unroll
      for (int n=0;n<4;++n)
        acc[m][n] = __builtin_amdgcn_mfma_f32_16x16x32_bf16(afr[m], bfr[n], acc[m][n], 0, 0, 0);
    __syncthreads();
  }
  // C/D layout: col = lane&15 (N side), row = (lane>>4)*4+q (M side)
  #pragma unroll
  for (int n=0;n<4;++n){
    const int scol = bn*128 + wn*64 + 16*n + (lane & 15);
    const float bias = bih[scol] + bhh[scol];
    #pragma unroll
    for (int m=0;m<4;++m){
      const int sr0 = bm*128 + wm*64 + 16*m + (lane >> 4)*4;
      #pragma unroll
      for (int q=0;q<4;++q){
        const float v = acc[m][n][q] + bias;
        const float vn = __shfl_xor(v, 1, 64);     // neighbor col (scol^1)
        if (!(lane & 1)){
          const unsigned word = f2bf(v) | (f2bf(vn) << 16);
          pre32[(size_t)(sr0 + q) * 1024 + (scol >> 1)] = word;
        }
      }
    }
  }
}

// ---------------------------------------------------------------- phase 2
// 512 independent waves; wave j0 owns h-lane j0 (gate rows {g*512+j0}).
// Lane l holds weight cols {2l+128c, 2l+128c+1 : c=0..3} (u64-load layout).
__global__ __launch_bounds__(256)
__attribute__((amdgpu_waves_per_eu(1,1)))
void lstm_seq(
    const float* __restrict__ Wih, const float* __restrict__ Whh,
    const unsigned* __restrict__ pre32, unsigned* __restrict__ units)
{
  const int tid = threadIdx.x;
  const int l = tid & 63;
  const int j0 = blockIdx.x * 4 + (tid >> 6);      // 0..511

  // ---- weights into VGPRs (once): col(k) = 2l + 128*(k>>1) + (k&1) ----
  float wh[4][8], wu[4][8];
  #pragma unroll
  for (int g=0; g<4; ++g){
    const float* ph = Whh + (size_t)(g*HDIM + j0)*HDIM;
    const float* pu = Wih + (size_t)(g*HDIM + j0)*IN5H + XDIM;
    #pragma unroll
    for (int k=0; k<8; ++k){
      const int col = 2*l + 128*(k>>1) + (k&1);
      wh[g][k] = ph[col]; wu[g][k] = pu[col];
    }
  }
  // Pin: opaque asm def blocks rematerialization/sinking of the loads.
  #pragma unroll
  for (int g=0; g<4; ++g)
    #pragma unroll
    for (int k=0; k<8; ++k){
      asm volatile("" : "+v"(wh[g][k]));
      asm volatile("" : "+v"(wu[g][k]));
    }

  const int phalf = j0 >> 1, psel = j0 & 1;
  float pr[4];
  #pragma unroll
  for (int g=0; g<4; ++g){
    const unsigned w0 = pre32[(size_t)0*1024 + g*256 + phalf];
    pr[g] = psel ? bfu(w0 >> 16) : bfu(w0 & 0xffffu);
  }

  float uvc[8];                       // u for current step (decoded)
  #pragma unroll
  for (int k=0;k<8;++k) uvc[k] = 0.f;

  float cst = 0.f;
  int dead = 0;

  for (int s = 0; s < NSTEP; ++s){
    // ---- issue ALL next-step loads first (share the poll's RT window) ----
    unsigned pw[4];
    const bool pf  = (s + 1 < NSTEP);
    const bool upf = (s + 1 >= 64) && pf;
    if (pf){
      #pragma unroll
      for (int g=0; g<4; ++g)
        pw[g] = pre32[(size_t)(s+1)*1024 + g*256 + phalf];   // plain, cached
    }
    unsigned long long un[4];
    if (upf){
      const unsigned long long* bp =
          (const unsigned long long*)(units + (size_t)(s-63)*HDIM) + l;
      #pragma unroll
      for (int c=0;c<4;++c)
        un[c] = __hip_atomic_load(bp + 64*c, __ATOMIC_RELAXED, __HIP_MEMORY_SCOPE_AGENT);
    }

    // ---- poll h[s-1] (both 4B halves tagged s) ----
    float hv[8];
    if (s == 0){
      #pragma unroll
      for (int k=0;k<8;++k) hv[k] = 0.f;
    } else {
      const unsigned long long* bp =
          (const unsigned long long*)(units + (size_t)(s-1)*HDIM) + l;
      unsigned long long v[4];
      if (dead){
        #pragma unroll
        for (int c=0;c<4;++c) v[c] = __hip_atomic_load(bp + 64*c, __ATOMIC_RELAXED, __HIP_MEMORY_SCOPE_AGENT);
      } else {
        int trips = 0, ok;
        do {
          #pragma unroll
          for (int c=0;c<4;++c) v[c] = __hip_atomic_load(bp + 64*c, __ATOMIC_RELAXED, __HIP_MEMORY_SCOPE_AGENT);
          int lok = 1;
          #pragma unroll
          for (int c=0;c<4;++c){
            lok &= (((unsigned)(v[c] >> 16) & 0xffffu) == (unsigned)s);
            lok &= (((unsigned)(v[c] >> 48)) == (unsigned)s);
          }
          ok = __all(lok);
        } while (!ok && ++trips < SPIN_LIMIT);
        if (!ok) dead = 1;
      }
      #pragma unroll
      for (int c=0;c<4;++c){
        hv[2*c]   = bfu((unsigned)v[c] & 0xffffu);
        hv[2*c+1] = bfu((unsigned)(v[c] >> 32) & 0xffffu);
      }
    }

    // ---- matvec: 4 gate rows x (8 h-cols + 8 u-cols) ----
    float a0=0.f, a1=0.f, a2=0.f, a3=0.f;
    #pragma unroll
    for (int k=0;k<8;++k){
      a0 += wh[0][k]*hv[k]; a1 += wh[1][k]*hv[k];
      a2 += wh[2][k]*hv[k]; a3 += wh[3][k]*hv[k];
    }
    #pragma unroll
    for (int k=0;k<8;++k){
      a0 += wu[0][k]*uvc[k]; a1 += wu[1][k]*uvc[k];
      a2 += wu[2][k]*uvc[k]; a3 += wu[3][k]*uvc[k];
    }
    a0 = wave_reduce63(a0);
    a1 = wave_reduce63(a1);
    a2 = wave_reduce63(a2);
    a3 = wave_reduce63(a3);

    // ---- pointwise (only lane 63's chain is valid; only it publishes) ----
    float gi = a0 + pr[0];
    float gf = a1 + pr[1];
    float gg = a2 + pr[2];
    float go = a3 + pr[3];
    gi = 1.f/(1.f + __expf(-gi));
    gf = 1.f/(1.f + __expf(-gf));
    go = 1.f/(1.f + __expf(-go));
    float e2 = __expf(2.f * fminf(fmaxf(gg, -15.f), 15.f));
    gg = (e2 - 1.f) / (e2 + 1.f);
    cst = gf*cst + gi*gg;
    float e2c = __expf(2.f * fminf(fmaxf(cst, -15.f), 15.f));
    const float hval = go * ((e2c - 1.f) / (e2c + 1.f));

    if (l == 63){
      const unsigned unit = ((unsigned)(s + 1) << 16) | f2bf(hval);
      __hip_atomic_store(units + (size_t)s*HDIM + j0, unit,
                         __ATOMIC_RELAXED, __HIP_MEMORY_SCOPE_AGENT);
    }

    // ---- finalize prefetches (off critical path) ----
    if (upf){
      int lok = 1;
      #pragma unroll
      for (int c=0;c<4;++c){
        lok &= (((unsigned)(un[c] >> 16) & 0xffffu) == (unsigned)(s-62));
        lok &= (((unsigned)(un[c] >> 48)) == (unsigned)(s-62));
      }
      if (!__all(lok) && !dead){
        // should never happen (62-step slack); bounded fallback spin
        const unsigned long long* bp =
            (const unsigned long long*)(units + (size_t)(s-63)*HDIM) + l;
        int trips = 0, ok;
        do {
          #pragma unroll
          for (int c=0;c<4;++c)
            un[c] = __hip_atomic_load(bp + 64*c, __ATOMIC_RELAXED, __HIP_MEMORY_SCOPE_AGENT);
          int lk = 1;
          #pragma unroll
          for (int c=0;c<4;++c){
            lk &= (((unsigned)(un[c] >> 16) & 0xffffu) == (unsigned)(s-62));
            lk &= (((unsigned)(un[c] >> 48)) == (unsigned)(s-62));
          }
          ok = __all(lk);
        } while (!ok && ++trips < SPIN_LIMIT);
        if (!ok) dead = 1;
      }
      #pragma unroll
      for (int c=0;c<4;++c){
        uvc[2*c]   = bfu((unsigned)un[c] & 0xffffu);
        uvc[2*c+1] = bfu((unsigned)(un[c] >> 32) & 0xffffu);
      }
    } else {
      #pragma unroll
      for (int k=0;k<8;++k) uvc[k] = 0.f;
    }
    if (pf){
      #pragma unroll
      for (int g=0; g<4; ++g)
        pr[g] = psel ? bfu(pw[g] >> 16) : bfu(pw[g] & 0xffffu);
    }
  }
}

// ---------------------------------------------------------------- phase 3
// y[b][t][lab] = sum_j h[s][j] * W_fc[lab][j] + b_fc[lab],  s = t*64 + b
__global__ __launch_bounds__(256) void fc_kernel(
    const unsigned* __restrict__ units,
    const float* __restrict__ Wfc, const float* __restrict__ bfc,
    float* __restrict__ out)
{
  __shared__ float hbuf[8][512];
  const int tid = threadIdx.x;
  const int s0 = blockIdx.x * 8;
  #pragma unroll
  for (int r=0;r<16;++r){
    const int q = tid + 256*r;                 // 0..4095
    const int si = q >> 9, j = q & 511;
    hbuf[si][j] = bfu(units[(size_t)(s0 + si)*HDIM + j] & 0xffffu);
  }
  __syncthreads();
  const int lab = tid & 127, sg = tid >> 7;
  const float* wrow = Wfc + (size_t)lab * HDIM;
  const float bias = bfc[lab];
  for (int si = sg; si < 8; si += 2){
    float sum = 0.f;
    #pragma unroll 4
    for (int j=0;j<HDIM;j+=4){
      const float4 wv = *(const float4*)(wrow + j);
      sum += wv.x*hbuf[si][j] + wv.y*hbuf[si][j+1]
           + wv.z*hbuf[si][j+2] + wv.w*hbuf[si][j+3];
    }
    const int s = s0 + si;
    const int bb = s & 63, tt = s >> 6;
    out[((size_t)(bb*LSEQ + tt))*LAB + lab] = sum + bias;
  }
}

__global__ void sentinel_kernel(float* out, int n){
  const int i = blockIdx.x*256 + threadIdx.x;
  if (i < n) out[i] = 12345.0f;     // diagnostic: ws_size too small
}

extern "C" void kernel_launch(void* const* d_in, const int* in_sizes, int n_in,
                              void* d_out, int out_size, void* d_ws, size_t ws_size,
                              hipStream_t stream)
{
  const float* x   = (const float*)d_in[0];
  const float* hi  = (const float*)d_in[1];
  const float* Wih = (const float*)d_in[2];
  const float* Whh = (const float*)d_in[3];
  const float* bih = (const float*)d_in[4];
  const float* bhh = (const float*)d_in[5];
  const float* Wfc = (const float*)d_in[6];
  const float* bfc = (const float*)d_in[7];
  float* out = (float*)d_out;

  const size_t MB = 1024*1024;
  if (ws_size >= 48*MB){
    unsigned* pre32 = (unsigned*)d_ws;                          // 32MB
    unsigned* units = (unsigned*)((char*)d_ws + 32*MB);         // 16MB
    gemm_pre<<<dim3(64, 16), 256, 0, stream>>>(x, hi, Wih, bih, bhh, pre32);
    lstm_seq<<<128, 256, 0, stream>>>(Wih, Whh, pre32, units);
    fc_kernel<<<1024, 256, 0, stream>>>(units, Wfc, bfc, out);
  } else {
    sentinel_kernel<<<(out_size + 255)/256, 256, 0, stream>>>(out, out_size);
  }
}